// Round 12
// baseline (975.826 us; speedup 1.0000x reference)
//
#include <hip/hip_runtime.h>

#define HID  64
#define SEQT 1024
#define NB   4

typedef _Float16 h8 __attribute__((ext_vector_type(8)));
typedef float    f4 __attribute__((ext_vector_type(4)));
typedef float    v2f __attribute__((ext_vector_type(2)));

__device__ __forceinline__ float rcpf(float x){ return __builtin_amdgcn_rcpf(x); }
__device__ __forceinline__ float sigm(float x){ return rcpf(1.0f + __expf(-x)); }
__device__ __forceinline__ float tanh_fast(float x){
    // 1 - 2/(e^{2x}+1); correct saturation at +-inf
    return 1.0f - 2.0f * rcpf(__expf(2.0f * x) + 1.0f);
}
__device__ __forceinline__ v2f pkfma(v2f a, v2f b, v2f c){
    return __builtin_elementwise_fma(a, b, c);      // -> v_pk_fma_f32
}

#define MFMA16(A,B,C) __builtin_amdgcn_mfma_f32_16x16x32_f16((A),(B),(C),0,0,0)

// split fp32 -> f16 hi + f16 lo (exact residual; 3-term product ~2^-24 rel)
__device__ __forceinline__ void split8(const float* __restrict__ p, h8& hi, h8& lo) {
    float4 u = *(const float4*)p;
    float4 v = *(const float4*)(p + 4);
    float vv[8] = {u.x, u.y, u.z, u.w, v.x, v.y, v.z, v.w};
    #pragma unroll
    for (int e = 0; e < 8; ++e) {
        _Float16 h = (_Float16)vv[e];
        hi[e] = h;
        lo[e] = (_Float16)(vv[e] - (float)h);
    }
}

// v11 math at 2x the TLP: 1024 threads = 16 waves = 4 waves/SIMD.
// Wave m owns M-tile m (gate rows 16m..16m+15) of BOTH pipelined layers:
// L0 = one C-chain of 6 MFMA, L1 = one C-chain of 12 (72 MFMA/SIMD/iter —
// the partition floor — unchanged; what changes is 4-way wave overlap hiding
// ds_read latency, cell VALU/trans, and barrier skew under MFMA).
// Per-wave regs: weights 48 + transient B-frags (two-phase load: b1 before
// L0 issues, b2 after) + accs ~ 110 < the 128 a 1024-thread block mandates.
// Cell: waves 0-3 cell0 (batch w), waves 4-7 cell1 (batch w-4), 8-15 idle.
// Double-buffered h, 2 barriers/iter, peeled x2 unroll (compile-time buffer
// indices), 63-iter-slack x prefetch, setprio around MFMA — all as v11.
__global__ __launch_bounds__(1024, 4)
void lstm2_v12(const float* __restrict__ x,
               const float* __restrict__ W_ih0, const float* __restrict__ W_hh0,
               const float* __restrict__ b_ih0, const float* __restrict__ b_hh0,
               const float* __restrict__ W_ih1, const float* __restrict__ W_hh1,
               const float* __restrict__ b_ih1, const float* __restrict__ b_hh1,
               const float* __restrict__ fc1_w, const float* __restrict__ fc1_b,
               const float* __restrict__ fc2_w, const float* __restrict__ fc2_b,
               float* __restrict__ out, int nblk)
{
    const int blk = blockIdx.x;
    if (blk >= nblk) return;
    const int tid = threadIdx.x;
    const int w   = tid >> 6;          // wave 0..15 = M-tile index
    const int l   = tid & 63;          // lane
    const int r16 = l & 15;            // A row in tile / D col (batch)
    const int g4  = l >> 4;            // k-subgroup / D row group
    const int cc  = r16 & 3;           // batch col for B-frag broadcast
    const int cb  = w & 3;             // cell batch (waves 0-7)
    const int B0  = blk * NB;

    // ---------------- LDS ----------------
    __shared__ __align__(16) _Float16 h1h[2][NB][80], h1l[2][NB][80];
    __shared__ __align__(16) _Float16 h2h[2][NB][80], h2l[2][NB][80];
    __shared__ __align__(16) float G0[NB][260];
    __shared__ __align__(16) float G1[NB][260];
    __shared__ __align__(16) float h2f[NB][64];

    // ---------------- A-fragments: ONE tile (rows 16w+r16), hi/lo ----------
    h8 a0[2][2];   // [ks][hi/lo]  W_hh0
    h8 a1[4][2];   // ks 0,1: W_ih1 ; ks 2,3: W_hh1
    {
        const int row = 16 * w + r16;
        #pragma unroll
        for (int ks = 0; ks < 2; ++ks) {
            split8(W_hh0 + row * HID + ks * 32 + g4 * 8, a0[ks][0],     a0[ks][1]);
            split8(W_ih1 + row * HID + ks * 32 + g4 * 8, a1[ks][0],     a1[ks][1]);
            split8(W_hh1 + row * HID + ks * 32 + g4 * 8, a1[2 + ks][0], a1[2 + ks][1]);
        }
    }

    // ---------------- cell constants, packed v2f (waves 0-7) ----------------
    const float* bip = (w < 4) ? b_ih0 : b_ih1;
    const float* bhp = (w < 4) ? b_hh0 : b_hh1;
    v2f biasA, biasB, wihA, wihB;
    biasA.x = bip[l]       + bhp[l];
    biasA.y = bip[l + 64]  + bhp[l + 64];
    biasB.x = bip[l + 128] + bhp[l + 128];
    biasB.y = bip[l + 192] + bhp[l + 192];
    if (w < 4) {
        wihA.x = W_ih0[l];       wihA.y = W_ih0[l + 64];
        wihB.x = W_ih0[l + 128]; wihB.y = W_ih0[l + 192];
    } else {
        wihA = (v2f){0.f, 0.f};  wihB = (v2f){0.f, 0.f};
    }

    // ---------------- init ----------------
    if (tid < 320) {   // 320 ints = 2*NB*80 halves per array
        ((int*)h1h)[tid] = 0; ((int*)h1l)[tid] = 0;
        ((int*)h2h)[tid] = 0; ((int*)h2l)[tid] = 0;
    }
    const size_t xbase = (size_t)(B0 + cb) * SEQT;
    float xc = 0.0f, xcn = 0.0f;
    if (w < 4) xc = x[xbase + l];      // chunk for t = 0..63 (lane = t offset)
    float cst = 0.0f;                  // c1 (waves 0-3) / c2 (waves 4-7)
    __syncthreads();

    const f4 z4 = {0.f, 0.f, 0.f, 0.f};

    // one pipelined iteration; RB/WB compile-time at every call site
    auto step = [&](int t_, int RB1, int RB2, int WB1, int WB2,
                    bool L0A, bool L1A, bool FIN) {
        if (w < 4 && ((t_ & 63) == 0) && (t_ + 64 < SEQT))
            xcn = x[xbase + t_ + 64 + l];

        // ---- phase-1 B-frags: h1(t-1) ----
        h8 b1h0 = *(const h8*)&h1h[RB1][cc][g4 * 8];
        h8 b1h1 = *(const h8*)&h1h[RB1][cc][32 + g4 * 8];
        h8 b1l0 = *(const h8*)&h1l[RB1][cc][g4 * 8];
        h8 b1l1 = *(const h8*)&h1l[RB1][cc][32 + g4 * 8];

        __builtin_amdgcn_s_setprio(1);
        if (L0A) {   // G0(t) = Whh0 * h1(t-1): one C-chain, depth 6
            f4 e = MFMA16(a0[0][0], b1h0, z4);
            e = MFMA16(a0[0][1], b1h0, e);
            e = MFMA16(a0[0][0], b1l0, e);
            e = MFMA16(a0[1][0], b1h1, e);
            e = MFMA16(a0[1][1], b1h1, e);
            e = MFMA16(a0[1][0], b1l1, e);
            if (r16 < NB)
                *(f4*)&G0[r16][16 * w + 4 * g4] = e;
        }
        if (L1A) {   // G1(t-1) = Wih1*h1(t-1) + Whh1*h2(t-2): one C-chain, 12
            // phase-2 B-frags loaded here: b1 regs die inside this chain
            h8 b2h0 = *(const h8*)&h2h[RB2][cc][g4 * 8];
            h8 b2h1 = *(const h8*)&h2h[RB2][cc][32 + g4 * 8];
            h8 b2l0 = *(const h8*)&h2l[RB2][cc][g4 * 8];
            h8 b2l1 = *(const h8*)&h2l[RB2][cc][32 + g4 * 8];
            f4 p = MFMA16(a1[0][0], b1h0, z4);
            p = MFMA16(a1[0][1], b1h0, p);
            p = MFMA16(a1[0][0], b1l0, p);
            p = MFMA16(a1[1][0], b1h1, p);
            p = MFMA16(a1[1][1], b1h1, p);
            p = MFMA16(a1[1][0], b1l1, p);
            p = MFMA16(a1[2][0], b2h0, p);
            p = MFMA16(a1[2][1], b2h0, p);
            p = MFMA16(a1[2][0], b2l0, p);
            p = MFMA16(a1[3][0], b2h1, p);
            p = MFMA16(a1[3][1], b2h1, p);
            p = MFMA16(a1[3][0], b2l1, p);
            if (r16 < NB)
                *(f4*)&G1[r16][16 * w + 4 * g4] = p;
        }
        __builtin_amdgcn_s_setprio(0);
        __syncthreads();                       // G0(t), G1(t-1) ready

        // ---- cell: waves 0-3 cell0(batch w); waves 4-7 cell1(batch w-4) ----
        if (w < 4) {
            if (L0A) {
                const float xt = __shfl(xc, t_ & 63);
                v2f xt2 = {xt, xt};
                v2f gA = {G0[w][l],       G0[w][l + 64]};
                v2f gB = {G0[w][l + 128], G0[w][l + 192]};
                v2f pA = gA + pkfma(xt2, wihA, biasA);
                v2f pB = gB + pkfma(xt2, wihB, biasB);
                float iv = sigm(pA.x), fv = sigm(pA.y);
                float gv = tanh_fast(pB.x), ov = sigm(pB.y);
                cst = fmaf(fv, cst, iv * gv);
                float hv = ov * tanh_fast(cst);
                _Float16 hh = (_Float16)hv;
                h1h[WB1][w][l] = hh;
                h1l[WB1][w][l] = (_Float16)(hv - (float)hh);
            }
        } else if (w < 8) {
            if (L1A) {
                v2f gA = {G1[cb][l],       G1[cb][l + 64]};
                v2f gB = {G1[cb][l + 128], G1[cb][l + 192]};
                v2f pA = gA + biasA;
                v2f pB = gB + biasB;
                float iv = sigm(pA.x), fv = sigm(pA.y);
                float gv = tanh_fast(pB.x), ov = sigm(pB.y);
                cst = fmaf(fv, cst, iv * gv);
                float hv = ov * tanh_fast(cst);
                _Float16 hh = (_Float16)hv;
                h2h[WB2][cb][l] = hh;
                h2l[WB2][cb][l] = (_Float16)(hv - (float)hh);
                if (FIN) h2f[cb][l] = hv;
            }
        }
        if ((t_ & 63) == 63) xc = xcn;
        __syncthreads();                       // h1(t), h2(t-1) ready
    };

    step(0, 1, 0, 0, 1, true,  false, false);
    step(1, 0, 1, 1, 0, true,  true,  false);
    #pragma unroll 1
    for (int t = 2; t < SEQT; t += 2) {
        step(t,     1, 0, 0, 1, true, true, false);
        step(t + 1, 0, 1, 1, 0, true, true, false);
    }
    step(SEQT, 1, 0, 0, 1, false, true, true);

    // ---------------- FC head: wave w (<4) -> batch w ----------------
    if (w < 4) {
        float z = 0.0f;
        if (l < 32) {
            float acc = fc1_b[l];
            const f4* hvp = (const f4*)h2f[w];
            const f4* wvp = (const f4*)(fc1_w + l * HID);
            #pragma unroll
            for (int q = 0; q < 16; ++q) {
                f4 hq = hvp[q], wk = wvp[q];
                acc = fmaf(hq[0], wk[0], acc); acc = fmaf(hq[1], wk[1], acc);
                acc = fmaf(hq[2], wk[2], acc); acc = fmaf(hq[3], wk[3], acc);
            }
            z = fmaxf(acc, 0.0f) * fc2_w[l];
        }
        #pragma unroll
        for (int off = 32; off > 0; off >>= 1) z += __shfl_xor(z, off);
        if (l == 0) out[B0 + w] = z + fc2_b[0];
    }
}

extern "C" void kernel_launch(void* const* d_in, const int* in_sizes, int n_in,
                              void* d_out, int out_size, void* d_ws, size_t ws_size,
                              hipStream_t stream) {
    const float* x     = (const float*)d_in[0];
    const float* W_ih0 = (const float*)d_in[1];
    const float* W_hh0 = (const float*)d_in[2];
    const float* b_ih0 = (const float*)d_in[3];
    const float* b_hh0 = (const float*)d_in[4];
    const float* W_ih1 = (const float*)d_in[5];
    const float* W_hh1 = (const float*)d_in[6];
    const float* b_ih1 = (const float*)d_in[7];
    const float* b_hh1 = (const float*)d_in[8];
    const float* fc1_w = (const float*)d_in[9];
    const float* fc1_b = (const float*)d_in[10];
    const float* fc2_w = (const float*)d_in[11];
    const float* fc2_b = (const float*)d_in[12];
    float* out = (float*)d_out;

    const int batch = in_sizes[0] / SEQT;   // 1024
    const int nblk  = batch / NB;           // 256 blocks, 1 per CU
    dim3 grid(nblk), block(1024);
    hipLaunchKernelGGL(lstm2_v12, grid, block, 0, stream,
                       x, W_ih0, W_hh0, b_ih0, b_hh0,
                       W_ih1, W_hh1, b_ih1, b_hh1,
                       fc1_w, fc1_b, fc2_w, fc2_b, out, nblk);
}